// Round 7
// baseline (422.588 us; speedup 1.0000x reference)
//
#include <hip/hip_runtime.h>
#include <hip/hip_bf16.h>

#define D_MODEL 1024
#define BATCH 8
#define SEQ 4096
#define MROWS (BATCH*SEQ)   // 32768
#define NC 64               // number of scan chunks
#define CL 64               // chunk length (NC*CL == SEQ)

typedef __attribute__((ext_vector_type(4))) float f32x4;
typedef __attribute__((ext_vector_type(8))) short s16x8;

__device__ __forceinline__ unsigned short f2bf(float f){
  union { float f; unsigned int u; } v; v.f = f;
  return (unsigned short)((v.u + 0x7fffu + ((v.u >> 16) & 1u)) >> 16);
}
__device__ __forceinline__ float bf2f(unsigned int bits){
  union { unsigned int u; float f; } v; v.u = bits << 16; return v.f;
}

__device__ __forceinline__ void gload16(const void* g, void* l){
  __builtin_amdgcn_global_load_lds(
      (const __attribute__((address_space(1))) unsigned int*)g,
      (__attribute__((address_space(3))) unsigned int*)l, 16, 0, 0);
}

// ---------------- prep (merged): x -> bf16 ; weights -> bf16 ; decay ----------------
__global__ __launch_bounds__(256)
void prep_all_kernel(const float* __restrict__ x,
                     const float* __restrict__ Wi, const float* __restrict__ Wg,
                     const float* __restrict__ Wo, const float* __restrict__ ld,
                     unsigned short* __restrict__ xb,
                     unsigned short* __restrict__ Wugb,   // stacked: Wi rows then Wg rows
                     unsigned short* __restrict__ Wob,
                     float* __restrict__ decay, int nx4){
  const int b = blockIdx.x;
  if (b < 8192){
    int i = b*256 + threadIdx.x;
    for (; i < nx4; i += 8192*256){
      float4 v = ((const float4*)x)[i];
      ushort4 o;
      o.x = f2bf(v.x); o.y = f2bf(v.y); o.z = f2bf(v.z); o.w = f2bf(v.w);
      ((ushort4*)xb)[i] = o;
    }
  } else {
    const int i = (b-8192)*256 + threadIdx.x;   // covers D*D/4 exactly (1024 blocks)
    float4 a = ((const float4*)Wi)[i]; ushort4 o;
    o.x=f2bf(a.x); o.y=f2bf(a.y); o.z=f2bf(a.z); o.w=f2bf(a.w); ((ushort4*)Wugb)[i]=o;
    a = ((const float4*)Wg)[i];
    o.x=f2bf(a.x); o.y=f2bf(a.y); o.z=f2bf(a.z); o.w=f2bf(a.w); ((ushort4*)Wugb)[i + D_MODEL*D_MODEL/4]=o;
    a = ((const float4*)Wo)[i];
    o.x=f2bf(a.x); o.y=f2bf(a.y); o.z=f2bf(a.z); o.w=f2bf(a.w); ((ushort4*)Wob)[i]=o;
    if (i < D_MODEL){
      float v = ld[i];
      float sp = fmaxf(v, 0.f) + log1pf(expf(-fabsf(v)));   // stable softplus
      decay[i] = sp + 1e-4f;
    }
  }
}

// ============ merged U+G GEMM: 128x128 m97 structure, B stacked (2048 rows) ============
// C[m][e] = sum_d X[m][d] * Wug[e][d]; cols<1024 -> ub (+b_in), cols>=1024 -> gb (+b_gate)
__global__ __launch_bounds__(256, 3)
void gemm_ug_kernel(const unsigned short* __restrict__ Aglob,
                    const unsigned short* __restrict__ Bglob,
                    const float* __restrict__ b_in,
                    const float* __restrict__ b_gate,
                    unsigned short* __restrict__ ub,
                    unsigned short* __restrict__ gb)
{
  __shared__ unsigned short sA[128*64];
  __shared__ unsigned short sB[128*64];
  const int tid  = threadIdx.x;
  const int lane = tid & 63;
  const int wave = tid >> 6;
  const int wr = wave >> 1, wc = wave & 1;
  // 4096 blocks = 8 XCD x (32 row-tiles x 16 col-tiles), col-fastest within XCD
  const int bid  = blockIdx.x;
  const int idx  = bid >> 3;
  const int xcd  = bid & 7;
  const int bcol = (idx & 15) * 128;                 // 0..1920
  const int brow = (xcd*32 + (idx >> 4)) * 128;      // 0..32640

  const f32x4 zero = {0.f,0.f,0.f,0.f};
  f32x4 acc[4][4];
  #pragma unroll
  for (int a=0;a<4;a++)
    #pragma unroll
    for (int b=0;b<4;b++) acc[a][b]=zero;

  for (int kt = 0; kt < D_MODEL/64; ++kt){
    __syncthreads();
    #pragma unroll
    for (int i=0;i<4;i++){
      const int ob = i*256 + wave*64;          // wave-uniform 16B-unit base
      const int o  = ob + lane;
      const int r  = o >> 3;                   // row 0..127
      const int c  = ((o & 7) ^ (r & 7)) * 16; // T2 content-swizzle (rule #21)
      gload16((const char*)Aglob + (size_t)(brow + r)*(D_MODEL*2) + (size_t)kt*128 + c,
              (char*)sA + (size_t)ob*16);
      gload16((const char*)Bglob + (size_t)(bcol + r)*(D_MODEL*2) + (size_t)kt*128 + c,
              (char*)sB + (size_t)ob*16);
    }
    __syncthreads();
    #pragma unroll
    for (int ks=0; ks<2; ++ks){
      s16x8 af[4], bf[4];
      #pragma unroll
      for (int mi=0; mi<4; mi++){
        const int row = wr*64 + mi*16 + (lane & 15);
        const int chunk = (ks*4 + (lane>>4)) ^ (row & 7);
        af[mi] = *(const s16x8*)((const char*)sA + row*128 + chunk*16);
      }
      #pragma unroll
      for (int ni=0; ni<4; ni++){
        const int n = wc*64 + ni*16 + (lane & 15);
        const int chunk = (ks*4 + (lane>>4)) ^ (n & 7);
        bf[ni] = *(const s16x8*)((const char*)sB + n*128 + chunk*16);
      }
      #pragma unroll
      for (int mi=0; mi<4; mi++)
        #pragma unroll
        for (int ni=0; ni<4; ni++)
          acc[mi][ni] = __builtin_amdgcn_mfma_f32_16x16x32_bf16(af[mi], bf[ni], acc[mi][ni], 0,0,0);
    }
  }

  const int half = bcol >> 10;                    // 0: update, 1: gate
  const float* bias = half ? b_gate : b_in;
  unsigned short* Co = half ? gb : ub;
  const int cb = bcol & 1023;
  #pragma unroll
  for (int ni=0; ni<4; ni++){
    const int col = cb + wc*64 + ni*16 + (lane & 15);
    const float vb = bias[col];
    #pragma unroll
    for (int mi=0; mi<4; mi++){
      #pragma unroll
      for (int q=0; q<4; q++){
        const int row = brow + wr*64 + mi*16 + ((lane>>4)*4) + q;
        Co[(size_t)row*D_MODEL + col] = f2bf(acc[mi][ni][q] + vb);
      }
    }
  }
}

// ------- scan pass A (fused): u,g_raw,delta -> lambda/drive -> pack + chunk reduce -------
__global__ __launch_bounds__(256)
void scan_passA(const unsigned short* __restrict__ ub,
                const unsigned short* __restrict__ gb,
                const float* __restrict__ delta,
                const float* __restrict__ decay,
                unsigned int* __restrict__ pack,
                float* __restrict__ cA, float* __restrict__ cB){
  const int d0 = (blockIdx.x*256 + threadIdx.x)*2;   // gridDim.x = D/512 = 2
  const int c = blockIdx.y, b = blockIdx.z;
  const float dc0 = decay[d0], dc1 = decay[d0+1];
  size_t base = ((size_t)b*SEQ + (size_t)c*CL)*D_MODEL + d0;
  float A0=1.f, A1=1.f, s0=0.f, s1=0.f;
  #pragma unroll 4
  for (int t=0;t<CL;t++){
    const size_t idx = base + (size_t)t*D_MODEL;
    const unsigned int uu = *(const unsigned int*)(ub + idx);
    const unsigned int gg = *(const unsigned int*)(gb + idx);
    const float2 dv = *(const float2*)(delta + idx);
    const float u0 = bf2f(uu & 0xffffu), u1 = bf2f(uu >> 16);
    const float z0 = bf2f(gg & 0xffffu), z1 = bf2f(gg >> 16);
    const float g0 = 1.f/(1.f + __expf(-z0));
    const float g1 = 1.f/(1.f + __expf(-z1));
    const float lam0 = __expf(-dc0 * fmaxf(dv.x, 1e-4f));
    const float lam1 = __expf(-dc1 * fmaxf(dv.y, 1e-4f));
    const float om0 = 1.f - lam0, om1 = 1.f - lam1;
    const float dr0 = om0 * g0 * u0;
    const float dr1 = om1 * g1 * u1;
    uint2 pw;
    pw.x = ((unsigned int)f2bf(dr0) << 16) | (unsigned int)f2bf(om0);
    pw.y = ((unsigned int)f2bf(dr1) << 16) | (unsigned int)f2bf(om1);
    *(uint2*)(pack + idx) = pw;
    A0 *= lam0; A1 *= lam1;
    s0 = fmaf(lam0, s0, dr0);
    s1 = fmaf(lam1, s1, dr1);
  }
  const size_t ci = ((size_t)b*NC + c)*D_MODEL + d0;
  *(float2*)(cA+ci) = make_float2(A0,A1);
  *(float2*)(cB+ci) = make_float2(s0,s1);
}

// ---------------- scan pass B: sequential chunk combine + final_state ----------------
__global__ __launch_bounds__(256)
void scan_passB(const float* __restrict__ cA, const float* __restrict__ cB,
                float* __restrict__ cS, float* __restrict__ fstate){
  const int d0 = (blockIdx.x*256 + threadIdx.x)*2;  // gridDim.x = 2
  const int b = blockIdx.y;
  float s0=0.f, s1=0.f;
  for (int c=0;c<NC;c++){
    const size_t ci = ((size_t)b*NC + c)*D_MODEL + d0;
    *(float2*)(cS+ci) = make_float2(s0,s1);
    float2 a  = *(const float2*)(cA+ci);
    float2 bb = *(const float2*)(cB+ci);
    s0 = fmaf(a.x, s0, bb.x);
    s1 = fmaf(a.y, s1, bb.y);
  }
  *(float2*)(fstate + (size_t)b*D_MODEL + d0) = make_float2(s0,s1);
}

// ---------------- scan pass C: re-scan chunks, emit states (bf16) ----------------
__global__ __launch_bounds__(256)
void scan_passC(const unsigned int* __restrict__ pack, const float* __restrict__ cS,
                unsigned short* __restrict__ statesb){
  const int d0 = (blockIdx.x*256 + threadIdx.x)*2;
  const int c = blockIdx.y, b = blockIdx.z;
  float2 sv = *(const float2*)(cS + ((size_t)b*NC + c)*D_MODEL + d0);
  float s0 = sv.x, s1 = sv.y;
  size_t base = ((size_t)b*SEQ + (size_t)c*CL)*D_MODEL + d0;
  #pragma unroll 8
  for (int t=0;t<CL;t++){
    uint2 p = *(const uint2*)(pack + base + (size_t)t*D_MODEL);
    float om0 = bf2f(p.x & 0xffffu), dr0 = bf2f(p.x >> 16);
    float om1 = bf2f(p.y & 0xffffu), dr1 = bf2f(p.y >> 16);
    s0 = fmaf(-om0, s0, s0) + dr0;   // s = (1-om)*s + dr, decay-precise
    s1 = fmaf(-om1, s1, s1) + dr1;
    unsigned int w = ((unsigned int)f2bf(s1) << 16) | (unsigned int)f2bf(s0);
    *(unsigned int*)(statesb + base + (size_t)t*D_MODEL) = w;
  }
}

// ---------- GEMM out + residual: yb = bf16(states Wout^T + b_out + states) ----------
// Residual states[row][col] is an element of this block's OWN A panel: when
// kt == bcol/64 + wc, the staged sA tile holds states[brow..+128][kt*64..+64].
// Snag it with one-time ds_read_u16 (swizzle-corrected) into acc.
__global__ __launch_bounds__(256, 3)
void gemm_out_kernel(const unsigned short* __restrict__ Sb,
                     const unsigned short* __restrict__ Wob,
                     const float* __restrict__ b_out,
                     unsigned short* __restrict__ yb)
{
  __shared__ unsigned short sA[128*64];
  __shared__ unsigned short sB[128*64];
  const int tid  = threadIdx.x;
  const int lane = tid & 63;
  const int wave = tid >> 6;
  const int wr = wave >> 1, wc = wave & 1;
  const int bid = blockIdx.x;
  const int swz = ((bid & 7) << 8) | (bid >> 3);
  const int bcol = (swz & 7) * 128;
  const int brow = (swz >> 3) * 128;

  const f32x4 zero = {0.f,0.f,0.f,0.f};
  f32x4 acc[4][4];
  #pragma unroll
  for (int a=0;a<4;a++)
    #pragma unroll
    for (int b=0;b<4;b++) acc[a][b]=zero;

  const int kt_res = (bcol >> 6) + wc;   // wave-uniform

  for (int kt = 0; kt < D_MODEL/64; ++kt){
    __syncthreads();
    #pragma unroll
    for (int i=0;i<4;i++){
      const int ob = i*256 + wave*64;
      const int o  = ob + lane;
      const int r  = o >> 3;
      const int c  = ((o & 7) ^ (r & 7)) * 16;
      gload16((const char*)Sb  + (size_t)(brow + r)*(D_MODEL*2) + (size_t)kt*128 + c,
              (char*)sA + (size_t)ob*16);
      gload16((const char*)Wob + (size_t)(bcol + r)*(D_MODEL*2) + (size_t)kt*128 + c,
              (char*)sB + (size_t)ob*16);
    }
    __syncthreads();
    #pragma unroll
    for (int ks=0; ks<2; ++ks){
      s16x8 af[4], bf[4];
      #pragma unroll
      for (int mi=0; mi<4; mi++){
        const int row = wr*64 + mi*16 + (lane & 15);
        const int chunk = (ks*4 + (lane>>4)) ^ (row & 7);
        af[mi] = *(const s16x8*)((const char*)sA + row*128 + chunk*16);
      }
      #pragma unroll
      for (int ni=0; ni<4; ni++){
        const int n = wc*64 + ni*16 + (lane & 15);
        const int chunk = (ks*4 + (lane>>4)) ^ (n & 7);
        bf[ni] = *(const s16x8*)((const char*)sB + n*128 + chunk*16);
      }
      #pragma unroll
      for (int mi=0; mi<4; mi++)
        #pragma unroll
        for (int ni=0; ni<4; ni++)
          acc[mi][ni] = __builtin_amdgcn_mfma_f32_16x16x32_bf16(af[mi], bf[ni], acc[mi][ni], 0,0,0);
    }
    if (kt == kt_res){
      // residual snag: states[row][col] from sA (still valid until next barrier)
      #pragma unroll
      for (int ni=0; ni<4; ni++){
        #pragma unroll
        for (int mi=0; mi<4; mi++){
          #pragma unroll
          for (int q=0; q<4; q++){
            const int rl = wr*64 + mi*16 + ((lane>>4)*4) + q;
            const int cl = ni*16 + (lane & 15);
            const int byte = rl*128 + (((cl>>3) ^ (rl&7))*16) + ((cl&7)*2);
            acc[mi][ni][q] += bf2f((unsigned int)*(const unsigned short*)((const char*)sA + byte));
          }
        }
      }
    }
  }

  #pragma unroll
  for (int ni=0; ni<4; ni++){
    const int col = bcol + wc*64 + ni*16 + (lane & 15);
    const float vb = b_out[col];
    #pragma unroll
    for (int mi=0; mi<4; mi++){
      #pragma unroll
      for (int q=0; q<4; q++){
        const int row = brow + wr*64 + mi*16 + ((lane>>4)*4) + q;
        yb[(size_t)row*D_MODEL + col] = f2bf(acc[mi][ni][q] + vb);
      }
    }
  }
}

// ---------------- LayerNorm (y already includes residual, bf16) ----------------
__global__ __launch_bounds__(256)
void ln_kernel(const unsigned short* __restrict__ yb,
               const float* __restrict__ gamma, const float* __restrict__ beta,
               float* __restrict__ out)
{
  const int row = blockIdx.x;
  const int tid = threadIdx.x;
  ushort4 yv = ((const ushort4*)(yb + (size_t)row*D_MODEL))[tid];
  float4 v;
  v.x = bf2f(yv.x); v.y = bf2f(yv.y); v.z = bf2f(yv.z); v.w = bf2f(yv.w);
  float s = v.x+v.y+v.z+v.w;
  float q = v.x*v.x + v.y*v.y + v.z*v.z + v.w*v.w;
  #pragma unroll
  for (int off=32; off>0; off>>=1){ s += __shfl_xor(s, off); q += __shfl_xor(q, off); }
  __shared__ float rs[4], rq[4];
  const int wave = tid>>6, lane = tid&63;
  if (lane==0){ rs[wave]=s; rq[wave]=q; }
  __syncthreads();
  float ts = rs[0]+rs[1]+rs[2]+rs[3];
  float tq = rq[0]+rq[1]+rq[2]+rq[3];
  float mu  = ts * (1.f/D_MODEL);
  float var = tq * (1.f/D_MODEL) - mu*mu;
  float inv = rsqrtf(var + 1e-5f);
  float4 g = ((const float4*)gamma)[tid];
  float4 b = ((const float4*)beta)[tid];
  float4 o;
  o.x = (v.x-mu)*inv*g.x + b.x;
  o.y = (v.y-mu)*inv*g.y + b.y;
  o.z = (v.z-mu)*inv*g.z + b.z;
  o.w = (v.w-mu)*inv*g.w + b.w;
  ((float4*)(out + (size_t)row*D_MODEL))[tid] = o;
}

extern "C" void kernel_launch(void* const* d_in, const int* in_sizes, int n_in,
                              void* d_out, int out_size, void* d_ws, size_t ws_size,
                              hipStream_t stream) {
  const float* x         = (const float*)d_in[0];
  const float* delta     = (const float*)d_in[1];
  const float* log_decay = (const float*)d_in[2];
  const float* W_in      = (const float*)d_in[3];
  const float* b_in      = (const float*)d_in[4];
  const float* W_gate    = (const float*)d_in[5];
  const float* b_gate    = (const float*)d_in[6];
  const float* W_out     = (const float*)d_in[7];
  const float* b_out     = (const float*)d_in[8];
  const float* gamma     = (const float*)d_in[9];
  const float* beta      = (const float*)d_in[10];

  char* w = (char*)d_ws;
  unsigned short* xb   = (unsigned short*)(w);                 // 64 MiB, reused as statesb
  unsigned short* Wugb = (unsigned short*)(w + 67108864);      // 4 MiB (Wi rows + Wg rows stacked)
  unsigned short* Wob  = (unsigned short*)(w + 71303168);      // 2 MiB
  float*          decay= (float*)        (w + 73400320);       // 4 KiB
  float*          cA   = (float*)        (w + 73404416);       // 2 MiB
  float*          cB   = (float*)        (w + 75501568);       // 2 MiB
  float*          cS   = (float*)        (w + 77598720);       // 2 MiB
  unsigned int*   pack = (unsigned int*) (w + 79695872);       // 128 MiB; first half reused as y(bf16)
  unsigned short* ybuf = (unsigned short*)pack;
  unsigned short* statesb = xb;

  float* out    = (float*)d_out;
  float* fstate = out + (size_t)MROWS*D_MODEL;
  // d_out's 128 MiB output area is dead until ln_kernel -> u/g bf16 scratch
  unsigned short* ub = (unsigned short*)d_out;                    // 64 MiB
  unsigned short* gb = ub + (size_t)MROWS*D_MODEL;                // 64 MiB

  hipLaunchKernelGGL(prep_all_kernel, dim3(9216), dim3(256), 0, stream,
                     x, W_in, W_gate, W_out, log_decay, xb, Wugb, Wob, decay, MROWS*D_MODEL/4);
  // merged u+g pass: ub/gb = bf16(X W^T + bias)
  hipLaunchKernelGGL(gemm_ug_kernel, dim3(4096), dim3(256), 0, stream,
                     xb, Wugb, b_in, b_gate, ub, gb);
  // fused elementwise + chunk reduction
  hipLaunchKernelGGL(scan_passA, dim3(2,NC,BATCH), dim3(256), 0, stream,
                     ub, gb, delta, decay, pack, cA, cB);
  hipLaunchKernelGGL(scan_passB, dim3(2,BATCH), dim3(256), 0, stream, cA, cB, cS, fstate);
  hipLaunchKernelGGL(scan_passC, dim3(2,NC,BATCH), dim3(256), 0, stream, pack, cS, statesb);
  // out-pass with fused residual: ybuf = bf16(states Wout^T + b_out + states)
  hipLaunchKernelGGL(gemm_out_kernel, dim3(2048), dim3(256), 0, stream,
                     statesb, Wob, b_out, ybuf);
  hipLaunchKernelGGL(ln_kernel, dim3(MROWS), dim3(256), 0, stream, ybuf, gamma, beta, out);
}

// Round 8
// 404.318 us; speedup vs baseline: 1.0452x; 1.0452x over previous
//
#include <hip/hip_runtime.h>
#include <hip/hip_bf16.h>

#define D_MODEL 1024
#define BATCH 8
#define SEQ 4096
#define MROWS (BATCH*SEQ)   // 32768
#define NC 64               // number of scan chunks
#define CL 64               // chunk length (NC*CL == SEQ)

typedef __attribute__((ext_vector_type(4))) float f32x4;
typedef __attribute__((ext_vector_type(8))) short s16x8;

__device__ __forceinline__ unsigned short f2bf(float f){
  union { float f; unsigned int u; } v; v.f = f;
  return (unsigned short)((v.u + 0x7fffu + ((v.u >> 16) & 1u)) >> 16);
}
__device__ __forceinline__ float bf2f(unsigned int bits){
  union { unsigned int u; float f; } v; v.u = bits << 16; return v.f;
}

__device__ __forceinline__ void gload16(const void* g, void* l){
  __builtin_amdgcn_global_load_lds(
      (const __attribute__((address_space(1))) unsigned int*)g,
      (__attribute__((address_space(3))) unsigned int*)l, 16, 0, 0);
}

// ------- prep (merged): x -> bf16 ; weights -> bf16 (Wi/Wg interleaved 64-row groups) -------
// Wugb layout: group g (g=0..15) = Wi rows [g*64,(g+1)*64) then Wg rows [g*64,(g+1)*64).
// So a 128-row contiguous slice starting at row g*128 is exactly the B panel for
// output cols [g*64,(g+1)*64) of BOTH gemms -> staging identical to a plain GEMM.
__global__ __launch_bounds__(256)
void prep_all_kernel(const float* __restrict__ x,
                     const float* __restrict__ Wi, const float* __restrict__ Wg,
                     const float* __restrict__ Wo, const float* __restrict__ ld,
                     unsigned short* __restrict__ xb,
                     unsigned short* __restrict__ Wugb,
                     unsigned short* __restrict__ Wob,
                     float* __restrict__ decay, int nx4){
  const int b = blockIdx.x;
  if (b < 8192){
    int i = b*256 + threadIdx.x;
    for (; i < nx4; i += 8192*256){
      float4 v = ((const float4*)x)[i];
      ushort4 o;
      o.x = f2bf(v.x); o.y = f2bf(v.y); o.z = f2bf(v.z); o.w = f2bf(v.w);
      ((ushort4*)xb)[i] = o;
    }
  } else {
    const int i = (b-8192)*256 + threadIdx.x;   // covers D*D/4 exactly (1024 blocks)
    const int row  = i >> 8;                    // source row (256 float4 per row)
    const int col4 = i & 255;
    const int g    = row >> 6;
    const int r    = row & 63;
    float4 a = ((const float4*)Wi)[i]; ushort4 o;
    o.x=f2bf(a.x); o.y=f2bf(a.y); o.z=f2bf(a.z); o.w=f2bf(a.w);
    ((ushort4*)Wugb)[(g*128 + r)*256 + col4] = o;
    a = ((const float4*)Wg)[i];
    o.x=f2bf(a.x); o.y=f2bf(a.y); o.z=f2bf(a.z); o.w=f2bf(a.w);
    ((ushort4*)Wugb)[(g*128 + 64 + r)*256 + col4] = o;
    a = ((const float4*)Wo)[i];
    o.x=f2bf(a.x); o.y=f2bf(a.y); o.z=f2bf(a.z); o.w=f2bf(a.w); ((ushort4*)Wob)[i]=o;
    if (i < D_MODEL){
      float v = ld[i];
      float sp = fmaxf(v, 0.f) + log1pf(expf(-fabsf(v)));   // stable softplus
      decay[i] = sp + 1e-4f;
    }
  }
}

// ===== slim dual GEMM: 128(M) x 64(N) tile, U and G accumulators, fused epilogue =====
// 64-reg total accumulator (same as single GEMM) -> 3 blocks/CU, unlike the
// round-2 dual (128+ regs, 2 blocks/CU, 26% MfmaUtil). Per-block staging volume
// and MFMA density identical to the merged ug kernel (8 gload16 + 32 MFMA / K-step).
// Epilogue: f32 u,z -> sigmoid/lambda/drive -> pack (no u/g round-trip to HBM).
__global__ __launch_bounds__(256, 3)
void gemm_dual64_kernel(const unsigned short* __restrict__ Xb,
                        const unsigned short* __restrict__ Wugb,
                        const float* __restrict__ b_in,
                        const float* __restrict__ b_gate,
                        const float* __restrict__ decay,
                        const float* __restrict__ delta,
                        unsigned int* __restrict__ pack)
{
  __shared__ unsigned short sA[128*64];
  __shared__ unsigned short sB[128*64];   // rows 0-63: Wi panel, rows 64-127: Wg panel
  const int tid  = threadIdx.x;
  const int lane = tid & 63;
  const int wave = tid >> 6;
  const int wr = wave >> 1, wc = wave & 1;
  // 4096 blocks = 8 XCD x (32 row-tiles x 16 col-tiles), col-fastest within XCD
  const int bid  = blockIdx.x;
  const int idx  = bid >> 3;
  const int xcd  = bid & 7;
  const int ct   = idx & 15;                     // col-tile (64 cols) == W group
  const int bcol = ct * 64;
  const int brow = (xcd*32 + (idx >> 4)) * 128;

  const f32x4 zero = {0.f,0.f,0.f,0.f};
  f32x4 accU[4][2], accG[4][2];
  #pragma unroll
  for (int a=0;a<4;a++)
    #pragma unroll
    for (int b=0;b<2;b++){ accU[a][b]=zero; accG[a][b]=zero; }

  for (int kt = 0; kt < D_MODEL/64; ++kt){
    __syncthreads();
    #pragma unroll
    for (int i=0;i<4;i++){
      const int ob = i*256 + wave*64;          // wave-uniform 16B-unit base
      const int o  = ob + lane;
      const int r  = o >> 3;                   // row 0..127
      const int c  = ((o & 7) ^ (r & 7)) * 16; // T2 content-swizzle (rule #21)
      gload16((const char*)Xb   + (size_t)(brow + r)*(D_MODEL*2) + (size_t)kt*128 + c,
              (char*)sA + (size_t)ob*16);
      gload16((const char*)Wugb + (size_t)(ct*128 + r)*(D_MODEL*2) + (size_t)kt*128 + c,
              (char*)sB + (size_t)ob*16);
    }
    __syncthreads();
    #pragma unroll
    for (int ks=0; ks<2; ++ks){
      s16x8 af[4], bu[2], bg[2];
      #pragma unroll
      for (int mi=0; mi<4; mi++){
        const int row = wr*64 + mi*16 + (lane & 15);
        const int chunk = (ks*4 + (lane>>4)) ^ (row & 7);
        af[mi] = *(const s16x8*)((const char*)sA + row*128 + chunk*16);
      }
      #pragma unroll
      for (int ni=0; ni<2; ni++){
        const int nu = wc*32 + ni*16 + (lane & 15);      // 0..63
        const int chunk = (ks*4 + (lane>>4)) ^ (nu & 7); // (nu+64)&7 == nu&7
        bu[ni] = *(const s16x8*)((const char*)sB + nu*128 + chunk*16);
        bg[ni] = *(const s16x8*)((const char*)sB + (nu+64)*128 + chunk*16);
      }
      #pragma unroll
      for (int mi=0; mi<4; mi++)
        #pragma unroll
        for (int ni=0; ni<2; ni++){
          accU[mi][ni] = __builtin_amdgcn_mfma_f32_16x16x32_bf16(af[mi], bu[ni], accU[mi][ni], 0,0,0);
          accG[mi][ni] = __builtin_amdgcn_mfma_f32_16x16x32_bf16(af[mi], bg[ni], accG[mi][ni], 0,0,0);
        }
    }
  }

  // epilogue: u,z (f32) -> lambda/drive, packed bf16x2 {drive(hi), 1-lambda(lo)}
  #pragma unroll
  for (int ni=0; ni<2; ni++){
    const int col = bcol + wc*32 + ni*16 + (lane & 15);
    const float vb = b_in[col], vg = b_gate[col], dc = decay[col];
    #pragma unroll
    for (int mi=0; mi<4; mi++){
      #pragma unroll
      for (int q=0; q<4; q++){
        const int row = brow + wr*64 + mi*16 + ((lane>>4)*4) + q;
        const size_t idx2 = (size_t)row*D_MODEL + col;
        const float u = accU[mi][ni][q] + vb;
        const float z = accG[mi][ni][q] + vg;
        const float g = 1.f/(1.f + __expf(-z));
        const float dt = fmaxf(delta[idx2], 1e-4f);
        const float lam = __expf(-dc*dt);
        const float omla = 1.f - lam;
        const float drv = omla * g * u;
        pack[idx2] = ((unsigned int)f2bf(drv) << 16) | (unsigned int)f2bf(omla);
      }
    }
  }
}

// ---------------- scan pass A: per-chunk (A = prod lam, B = local scan) ----------------
__global__ __launch_bounds__(256)
void scan_passA(const unsigned int* __restrict__ pack, float* __restrict__ cA, float* __restrict__ cB){
  const int d0 = (blockIdx.x*256 + threadIdx.x)*2;   // gridDim.x = D/512 = 2
  const int c = blockIdx.y, b = blockIdx.z;
  size_t base = ((size_t)b*SEQ + (size_t)c*CL)*D_MODEL + d0;
  float A0=1.f, A1=1.f, s0=0.f, s1=0.f;
  #pragma unroll 8
  for (int t=0;t<CL;t++){
    uint2 p = *(const uint2*)(pack + base + (size_t)t*D_MODEL);
    float om0 = bf2f(p.x & 0xffffu), dr0 = bf2f(p.x >> 16);
    float om1 = bf2f(p.y & 0xffffu), dr1 = bf2f(p.y >> 16);
    float l0 = 1.f - om0, l1 = 1.f - om1;
    A0 *= l0; A1 *= l1;
    s0 = fmaf(l0, s0, dr0);
    s1 = fmaf(l1, s1, dr1);
  }
  const size_t ci = ((size_t)b*NC + c)*D_MODEL + d0;
  *(float2*)(cA+ci) = make_float2(A0,A1);
  *(float2*)(cB+ci) = make_float2(s0,s1);
}

// ---------------- scan pass B: sequential chunk combine + final_state ----------------
__global__ __launch_bounds__(256)
void scan_passB(const float* __restrict__ cA, const float* __restrict__ cB,
                float* __restrict__ cS, float* __restrict__ fstate){
  const int d0 = (blockIdx.x*256 + threadIdx.x)*2;  // gridDim.x = 2
  const int b = blockIdx.y;
  float s0=0.f, s1=0.f;
  for (int c=0;c<NC;c++){
    const size_t ci = ((size_t)b*NC + c)*D_MODEL + d0;
    *(float2*)(cS+ci) = make_float2(s0,s1);
    float2 a  = *(const float2*)(cA+ci);
    float2 bb = *(const float2*)(cB+ci);
    s0 = fmaf(a.x, s0, bb.x);
    s1 = fmaf(a.y, s1, bb.y);
  }
  *(float2*)(fstate + (size_t)b*D_MODEL + d0) = make_float2(s0,s1);
}

// ---------------- scan pass C: re-scan chunks, emit states (bf16) ----------------
__global__ __launch_bounds__(256)
void scan_passC(const unsigned int* __restrict__ pack, const float* __restrict__ cS,
                unsigned short* __restrict__ statesb){
  const int d0 = (blockIdx.x*256 + threadIdx.x)*2;
  const int c = blockIdx.y, b = blockIdx.z;
  float2 sv = *(const float2*)(cS + ((size_t)b*NC + c)*D_MODEL + d0);
  float s0 = sv.x, s1 = sv.y;
  size_t base = ((size_t)b*SEQ + (size_t)c*CL)*D_MODEL + d0;
  #pragma unroll 8
  for (int t=0;t<CL;t++){
    uint2 p = *(const uint2*)(pack + base + (size_t)t*D_MODEL);
    float om0 = bf2f(p.x & 0xffffu), dr0 = bf2f(p.x >> 16);
    float om1 = bf2f(p.y & 0xffffu), dr1 = bf2f(p.y >> 16);
    s0 = fmaf(-om0, s0, s0) + dr0;   // s = (1-om)*s + dr, decay-precise
    s1 = fmaf(-om1, s1, s1) + dr1;
    unsigned int w = ((unsigned int)f2bf(s1) << 16) | (unsigned int)f2bf(s0);
    *(unsigned int*)(statesb + base + (size_t)t*D_MODEL) = w;
  }
}

// ---------- GEMM out + residual: yb = bf16(states Wout^T + b_out + states) ----------
__global__ __launch_bounds__(256, 3)
void gemm_out_kernel(const unsigned short* __restrict__ Sb,
                     const unsigned short* __restrict__ Wob,
                     const float* __restrict__ b_out,
                     unsigned short* __restrict__ yb)
{
  __shared__ unsigned short sA[128*64];
  __shared__ unsigned short sB[128*64];
  const int tid  = threadIdx.x;
  const int lane = tid & 63;
  const int wave = tid >> 6;
  const int wr = wave >> 1, wc = wave & 1;
  const int bid = blockIdx.x;
  const int swz = ((bid & 7) << 8) | (bid >> 3);
  const int bcol = (swz & 7) * 128;
  const int brow = (swz >> 3) * 128;

  const f32x4 zero = {0.f,0.f,0.f,0.f};
  f32x4 acc[4][4];
  #pragma unroll
  for (int a=0;a<4;a++)
    #pragma unroll
    for (int b=0;b<4;b++) acc[a][b]=zero;

  const int kt_res = (bcol >> 6) + wc;   // wave-uniform

  for (int kt = 0; kt < D_MODEL/64; ++kt){
    __syncthreads();
    #pragma unroll
    for (int i=0;i<4;i++){
      const int ob = i*256 + wave*64;
      const int o  = ob + lane;
      const int r  = o >> 3;
      const int c  = ((o & 7) ^ (r & 7)) * 16;
      gload16((const char*)Sb  + (size_t)(brow + r)*(D_MODEL*2) + (size_t)kt*128 + c,
              (char*)sA + (size_t)ob*16);
      gload16((const char*)Wob + (size_t)(bcol + r)*(D_MODEL*2) + (size_t)kt*128 + c,
              (char*)sB + (size_t)ob*16);
    }
    __syncthreads();
    #pragma unroll
    for (int ks=0; ks<2; ++ks){
      s16x8 af[4], bf[4];
      #pragma unroll
      for (int mi=0; mi<4; mi++){
        const int row = wr*64 + mi*16 + (lane & 15);
        const int chunk = (ks*4 + (lane>>4)) ^ (row & 7);
        af[mi] = *(const s16x8*)((const char*)sA + row*128 + chunk*16);
      }
      #pragma unroll
      for (int ni=0; ni<4; ni++){
        const int n = wc*64 + ni*16 + (lane & 15);
        const int chunk = (ks*4 + (lane>>4)) ^ (n & 7);
        bf[ni] = *(const s16x8*)((const char*)sB + n*128 + chunk*16);
      }
      #pragma unroll
      for (int mi=0; mi<4; mi++)
        #pragma unroll
        for (int ni=0; ni<4; ni++)
          acc[mi][ni] = __builtin_amdgcn_mfma_f32_16x16x32_bf16(af[mi], bf[ni], acc[mi][ni], 0,0,0);
    }
    if (kt == kt_res){
      // residual snag: states[row][col] from sA (valid until next barrier)
      #pragma unroll
      for (int ni=0; ni<4; ni++){
        #pragma unroll
        for (int mi=0; mi<4; mi++){
          #pragma unroll
          for (int q=0; q<4; q++){
            const int rl = wr*64 + mi*16 + ((lane>>4)*4) + q;
            const int cl = ni*16 + (lane & 15);
            const int byte = rl*128 + (((cl>>3) ^ (rl&7))*16) + ((cl&7)*2);
            acc[mi][ni][q] += bf2f((unsigned int)*(const unsigned short*)((const char*)sA + byte));
          }
        }
      }
    }
  }

  #pragma unroll
  for (int ni=0; ni<4; ni++){
    const int col = bcol + wc*64 + ni*16 + (lane & 15);
    const float vb = b_out[col];
    #pragma unroll
    for (int mi=0; mi<4; mi++){
      #pragma unroll
      for (int q=0; q<4; q++){
        const int row = brow + wr*64 + mi*16 + ((lane>>4)*4) + q;
        yb[(size_t)row*D_MODEL + col] = f2bf(acc[mi][ni][q] + vb);
      }
    }
  }
}

// ---------------- LayerNorm (y already includes residual, bf16) ----------------
__global__ __launch_bounds__(256)
void ln_kernel(const unsigned short* __restrict__ yb,
               const float* __restrict__ gamma, const float* __restrict__ beta,
               float* __restrict__ out)
{
  const int row = blockIdx.x;
  const int tid = threadIdx.x;
  ushort4 yv = ((const ushort4*)(yb + (size_t)row*D_MODEL))[tid];
  float4 v;
  v.x = bf2f(yv.x); v.y = bf2f(yv.y); v.z = bf2f(yv.z); v.w = bf2f(yv.w);
  float s = v.x+v.y+v.z+v.w;
  float q = v.x*v.x + v.y*v.y + v.z*v.z + v.w*v.w;
  #pragma unroll
  for (int off=32; off>0; off>>=1){ s += __shfl_xor(s, off); q += __shfl_xor(q, off); }
  __shared__ float rs[4], rq[4];
  const int wave = tid>>6, lane = tid&63;
  if (lane==0){ rs[wave]=s; rq[wave]=q; }
  __syncthreads();
  float ts = rs[0]+rs[1]+rs[2]+rs[3];
  float tq = rq[0]+rq[1]+rq[2]+rq[3];
  float mu  = ts * (1.f/D_MODEL);
  float var = tq * (1.f/D_MODEL) - mu*mu;
  float inv = rsqrtf(var + 1e-5f);
  float4 g = ((const float4*)gamma)[tid];
  float4 b = ((const float4*)beta)[tid];
  float4 o;
  o.x = (v.x-mu)*inv*g.x + b.x;
  o.y = (v.y-mu)*inv*g.y + b.y;
  o.z = (v.z-mu)*inv*g.z + b.z;
  o.w = (v.w-mu)*inv*g.w + b.w;
  ((float4*)(out + (size_t)row*D_MODEL))[tid] = o;
}

extern "C" void kernel_launch(void* const* d_in, const int* in_sizes, int n_in,
                              void* d_out, int out_size, void* d_ws, size_t ws_size,
                              hipStream_t stream) {
  const float* x         = (const float*)d_in[0];
  const float* delta     = (const float*)d_in[1];
  const float* log_decay = (const float*)d_in[2];
  const float* W_in      = (const float*)d_in[3];
  const float* b_in      = (const float*)d_in[4];
  const float* W_gate    = (const float*)d_in[5];
  const float* b_gate    = (const float*)d_in[6];
  const float* W_out     = (const float*)d_in[7];
  const float* b_out     = (const float*)d_in[8];
  const float* gamma     = (const float*)d_in[9];
  const float* beta      = (const float*)d_in[10];

  char* w = (char*)d_ws;
  unsigned short* xb   = (unsigned short*)(w);                 // 64 MiB, reused as statesb
  unsigned short* Wugb = (unsigned short*)(w + 67108864);      // 4 MiB (interleaved Wi/Wg groups)
  unsigned short* Wob  = (unsigned short*)(w + 71303168);      // 2 MiB
  float*          decay= (float*)        (w + 73400320);       // 4 KiB
  float*          cA   = (float*)        (w + 73404416);       // 2 MiB
  float*          cB   = (float*)        (w + 75501568);       // 2 MiB
  float*          cS   = (float*)        (w + 77598720);       // 2 MiB
  unsigned int*   pack = (unsigned int*) (w + 79695872);       // 128 MiB; first half reused as y(bf16)
  unsigned short* ybuf = (unsigned short*)pack;
  unsigned short* statesb = xb;

  float* out    = (float*)d_out;
  float* fstate = out + (size_t)MROWS*D_MODEL;

  hipLaunchKernelGGL(prep_all_kernel, dim3(9216), dim3(256), 0, stream,
                     x, W_in, W_gate, W_out, log_decay, xb, Wugb, Wob, decay, MROWS*D_MODEL/4);
  // slim dual GEMM: pack = {drive, 1-lambda} directly (no u/g round-trip)
  hipLaunchKernelGGL(gemm_dual64_kernel, dim3(4096), dim3(256), 0, stream,
                     xb, Wugb, b_in, b_gate, decay, delta, pack);
  hipLaunchKernelGGL(scan_passA, dim3(2,NC,BATCH), dim3(256), 0, stream, pack, cA, cB);
  hipLaunchKernelGGL(scan_passB, dim3(2,BATCH), dim3(256), 0, stream, cA, cB, cS, fstate);
  hipLaunchKernelGGL(scan_passC, dim3(2,NC,BATCH), dim3(256), 0, stream, pack, cS, statesb);
  // out-pass with fused residual: ybuf = bf16(states Wout^T + b_out + states)
  hipLaunchKernelGGL(gemm_out_kernel, dim3(2048), dim3(256), 0, stream,
                     statesb, Wob, b_out, ybuf);
  hipLaunchKernelGGL(ln_kernel, dim3(MROWS), dim3(256), 0, stream, ybuf, gamma, beta, out);
}

// Round 9
// 399.167 us; speedup vs baseline: 1.0587x; 1.0129x over previous
//
#include <hip/hip_runtime.h>
#include <hip/hip_bf16.h>

#define D_MODEL 1024
#define BATCH 8
#define SEQ 4096
#define MROWS (BATCH*SEQ)   // 32768
#define NC 64               // number of scan chunks
#define CL 64               // chunk length (NC*CL == SEQ)

typedef __attribute__((ext_vector_type(4))) float f32x4;
typedef __attribute__((ext_vector_type(8))) short s16x8;

__device__ __forceinline__ unsigned short f2bf(float f){
  union { float f; unsigned int u; } v; v.f = f;
  return (unsigned short)((v.u + 0x7fffu + ((v.u >> 16) & 1u)) >> 16);
}
__device__ __forceinline__ float bf2f(unsigned int bits){
  union { unsigned int u; float f; } v; v.u = bits << 16; return v.f;
}

__device__ __forceinline__ void gload16(const void* g, void* l){
  __builtin_amdgcn_global_load_lds(
      (const __attribute__((address_space(1))) unsigned int*)g,
      (__attribute__((address_space(3))) unsigned int*)l, 16, 0, 0);
}

// ------- prep (merged): x -> bf16 ; weights -> bf16 (Wi/Wg interleaved 64-row groups) -------
// Wugb layout: group g (g=0..15) = Wi rows [g*64,(g+1)*64) then Wg rows [g*64,(g+1)*64).
__global__ __launch_bounds__(256)
void prep_all_kernel(const float* __restrict__ x,
                     const float* __restrict__ Wi, const float* __restrict__ Wg,
                     const float* __restrict__ Wo, const float* __restrict__ ld,
                     unsigned short* __restrict__ xb,
                     unsigned short* __restrict__ Wugb,
                     unsigned short* __restrict__ Wob,
                     float* __restrict__ decay, int nx4){
  const int b = blockIdx.x;
  if (b < 8192){
    int i = b*256 + threadIdx.x;
    for (; i < nx4; i += 8192*256){
      float4 v = ((const float4*)x)[i];
      ushort4 o;
      o.x = f2bf(v.x); o.y = f2bf(v.y); o.z = f2bf(v.z); o.w = f2bf(v.w);
      ((ushort4*)xb)[i] = o;
    }
  } else {
    const int i = (b-8192)*256 + threadIdx.x;   // covers D*D/4 exactly (1024 blocks)
    const int row  = i >> 8;                    // source row (256 float4 per row)
    const int col4 = i & 255;
    const int g    = row >> 6;
    const int r    = row & 63;
    float4 a = ((const float4*)Wi)[i]; ushort4 o;
    o.x=f2bf(a.x); o.y=f2bf(a.y); o.z=f2bf(a.z); o.w=f2bf(a.w);
    ((ushort4*)Wugb)[(g*128 + r)*256 + col4] = o;
    a = ((const float4*)Wg)[i];
    o.x=f2bf(a.x); o.y=f2bf(a.y); o.z=f2bf(a.z); o.w=f2bf(a.w);
    ((ushort4*)Wugb)[(g*128 + 64 + r)*256 + col4] = o;
    a = ((const float4*)Wo)[i];
    o.x=f2bf(a.x); o.y=f2bf(a.y); o.z=f2bf(a.z); o.w=f2bf(a.w); ((ushort4*)Wob)[i]=o;
    if (i < D_MODEL){
      float v = ld[i];
      float sp = fmaxf(v, 0.f) + log1pf(expf(-fabsf(v)));   // stable softplus
      decay[i] = sp + 1e-4f;
    }
  }
}

// ===== slim dual GEMM: 128(M) x 64(N), U+G accumulators, fused epilogue =====
// Epilogue: f32 u,z -> sigmoid/lambda/drive -> pack, AND in-register chunk-summary
// (passA fused): each wave's wr-half is exactly one 64-t scan chunk; q-values are
// 4 consecutive t. Compose (A,B) per thread, shfl_xor across g=lane>>4 (t-ordered),
// then serial over mi. Summaries use bf16-quantized om/drv (identical to old passA).
__global__ __launch_bounds__(256, 3)
void gemm_dual64_kernel(const unsigned short* __restrict__ Xb,
                        const unsigned short* __restrict__ Wugb,
                        const float* __restrict__ b_in,
                        const float* __restrict__ b_gate,
                        const float* __restrict__ decay,
                        const float* __restrict__ delta,
                        unsigned int* __restrict__ pack,
                        float* __restrict__ cA, float* __restrict__ cB)
{
  __shared__ unsigned short sA[128*64];
  __shared__ unsigned short sB[128*64];   // rows 0-63: Wi panel, rows 64-127: Wg panel
  const int tid  = threadIdx.x;
  const int lane = tid & 63;
  const int wave = tid >> 6;
  const int wr = wave >> 1, wc = wave & 1;
  // 4096 blocks = 8 XCD x (32 row-tiles x 16 col-tiles), col-fastest within XCD
  const int bid  = blockIdx.x;
  const int idx  = bid >> 3;
  const int xcd  = bid & 7;
  const int ct   = idx & 15;                     // col-tile (64 cols) == W group
  const int bcol = ct * 64;
  const int brow = (xcd*32 + (idx >> 4)) * 128;

  const f32x4 zero = {0.f,0.f,0.f,0.f};
  f32x4 accU[4][2], accG[4][2];
  #pragma unroll
  for (int a=0;a<4;a++)
    #pragma unroll
    for (int b=0;b<2;b++){ accU[a][b]=zero; accG[a][b]=zero; }

  for (int kt = 0; kt < D_MODEL/64; ++kt){
    __syncthreads();
    #pragma unroll
    for (int i=0;i<4;i++){
      const int ob = i*256 + wave*64;          // wave-uniform 16B-unit base
      const int o  = ob + lane;
      const int r  = o >> 3;                   // row 0..127
      const int c  = ((o & 7) ^ (r & 7)) * 16; // T2 content-swizzle (rule #21)
      gload16((const char*)Xb   + (size_t)(brow + r)*(D_MODEL*2) + (size_t)kt*128 + c,
              (char*)sA + (size_t)ob*16);
      gload16((const char*)Wugb + (size_t)(ct*128 + r)*(D_MODEL*2) + (size_t)kt*128 + c,
              (char*)sB + (size_t)ob*16);
    }
    __syncthreads();
    #pragma unroll
    for (int ks=0; ks<2; ++ks){
      s16x8 af[4], bu[2], bg[2];
      #pragma unroll
      for (int mi=0; mi<4; mi++){
        const int row = wr*64 + mi*16 + (lane & 15);
        const int chunk = (ks*4 + (lane>>4)) ^ (row & 7);
        af[mi] = *(const s16x8*)((const char*)sA + row*128 + chunk*16);
      }
      #pragma unroll
      for (int ni=0; ni<2; ni++){
        const int nu = wc*32 + ni*16 + (lane & 15);      // 0..63
        const int chunk = (ks*4 + (lane>>4)) ^ (nu & 7); // (nu+64)&7 == nu&7
        bu[ni] = *(const s16x8*)((const char*)sB + nu*128 + chunk*16);
        bg[ni] = *(const s16x8*)((const char*)sB + (nu+64)*128 + chunk*16);
      }
      #pragma unroll
      for (int mi=0; mi<4; mi++)
        #pragma unroll
        for (int ni=0; ni<2; ni++){
          accU[mi][ni] = __builtin_amdgcn_mfma_f32_16x16x32_bf16(af[mi], bu[ni], accU[mi][ni], 0,0,0);
          accG[mi][ni] = __builtin_amdgcn_mfma_f32_16x16x32_bf16(af[mi], bg[ni], accG[mi][ni], 0,0,0);
        }
    }
  }

  // epilogue: lambda/drive -> pack + fused chunk-summary
  const int t0 = brow + wr*64;         // this wave's chunk start (global row)
  const int bb = t0 >> 12;             // batch  (t0 / 4096)
  const int cc = (t0 & 4095) >> 6;     // chunk  ((t0 % 4096) / 64)
  const int g  = lane >> 4;            // 4-t segment slot within 16-t mi group

  #pragma unroll
  for (int ni=0; ni<2; ni++){
    const int col = bcol + wc*32 + ni*16 + (lane & 15);
    const float vb = b_in[col], vg = b_gate[col], dc = decay[col];
    float runA = 1.f, runB = 0.f;
    #pragma unroll
    for (int mi=0; mi<4; mi++){
      float segA = 1.f, segB = 0.f;
      #pragma unroll
      for (int q=0; q<4; q++){
        const int row = brow + wr*64 + mi*16 + g*4 + q;
        const size_t idx2 = (size_t)row*D_MODEL + col;
        const float u = accU[mi][ni][q] + vb;
        const float z = accG[mi][ni][q] + vg;
        const float gt = 1.f/(1.f + __expf(-z));
        const float dt = fmaxf(delta[idx2], 1e-4f);
        const float lam = __expf(-dc*dt);
        const float omla = 1.f - lam;
        const float drv = omla * gt * u;
        const unsigned short omb = f2bf(omla);
        const unsigned short drb = f2bf(drv);
        pack[idx2] = ((unsigned int)drb << 16) | (unsigned int)omb;
        // quantized values (match passC's inputs) for the summary
        const float lam_q = 1.f - bf2f((unsigned int)omb);
        const float dr_q  = bf2f((unsigned int)drb);
        segA *= lam_q;
        segB = fmaf(lam_q, segB, dr_q);
      }
      // compose across g in t-order: (A_X,B_X) then (A_Y,B_Y) -> (A_X*A_Y, B_X*A_Y+B_Y)
      {
        float pA = __shfl_xor(segA, 16);
        float pB = __shfl_xor(segB, 16);
        if (g & 1){ segB = fmaf(pB, segA, segB); segA = pA * segA; }
        else      { segB = fmaf(segB, pA, pB);   segA = segA * pA; }
        pA = __shfl_xor(segA, 32);
        pB = __shfl_xor(segB, 32);
        if (g & 2){ segB = fmaf(pB, segA, segB); segA = pA * segA; }
        else      { segB = fmaf(segB, pA, pB);   segA = segA * pA; }
      }
      // running (earlier t) ⊕ seg16 (later t)
      runB = fmaf(runB, segA, segB);
      runA *= segA;
    }
    if (g == 0){
      const size_t ci = ((size_t)bb*NC + cc)*D_MODEL + col;
      cA[ci] = runA;
      cB[ci] = runB;
    }
  }
}

// ---------------- scan pass B: sequential chunk combine + final_state ----------------
__global__ __launch_bounds__(256)
void scan_passB(const float* __restrict__ cA, const float* __restrict__ cB,
                float* __restrict__ cS, float* __restrict__ fstate){
  const int d0 = (blockIdx.x*256 + threadIdx.x)*2;  // gridDim.x = 2
  const int b = blockIdx.y;
  float s0=0.f, s1=0.f;
  for (int c=0;c<NC;c++){
    const size_t ci = ((size_t)b*NC + c)*D_MODEL + d0;
    *(float2*)(cS+ci) = make_float2(s0,s1);
    float2 a  = *(const float2*)(cA+ci);
    float2 bb = *(const float2*)(cB+ci);
    s0 = fmaf(a.x, s0, bb.x);
    s1 = fmaf(a.y, s1, bb.y);
  }
  *(float2*)(fstate + (size_t)b*D_MODEL + d0) = make_float2(s0,s1);
}

// ---------------- scan pass C: re-scan chunks, emit states (bf16) ----------------
__global__ __launch_bounds__(256)
void scan_passC(const unsigned int* __restrict__ pack, const float* __restrict__ cS,
                unsigned short* __restrict__ statesb){
  const int d0 = (blockIdx.x*256 + threadIdx.x)*2;
  const int c = blockIdx.y, b = blockIdx.z;
  float2 sv = *(const float2*)(cS + ((size_t)b*NC + c)*D_MODEL + d0);
  float s0 = sv.x, s1 = sv.y;
  size_t base = ((size_t)b*SEQ + (size_t)c*CL)*D_MODEL + d0;
  #pragma unroll 8
  for (int t=0;t<CL;t++){
    uint2 p = *(const uint2*)(pack + base + (size_t)t*D_MODEL);
    float om0 = bf2f(p.x & 0xffffu), dr0 = bf2f(p.x >> 16);
    float om1 = bf2f(p.y & 0xffffu), dr1 = bf2f(p.y >> 16);
    s0 = fmaf(-om0, s0, s0) + dr0;   // s = (1-om)*s + dr, decay-precise
    s1 = fmaf(-om1, s1, s1) + dr1;
    unsigned int w = ((unsigned int)f2bf(s1) << 16) | (unsigned int)f2bf(s0);
    *(unsigned int*)(statesb + base + (size_t)t*D_MODEL) = w;
  }
}

// ---------- GEMM out + residual: yb = bf16(states Wout^T + b_out + states) ----------
__global__ __launch_bounds__(256, 3)
void gemm_out_kernel(const unsigned short* __restrict__ Sb,
                     const unsigned short* __restrict__ Wob,
                     const float* __restrict__ b_out,
                     unsigned short* __restrict__ yb)
{
  __shared__ unsigned short sA[128*64];
  __shared__ unsigned short sB[128*64];
  const int tid  = threadIdx.x;
  const int lane = tid & 63;
  const int wave = tid >> 6;
  const int wr = wave >> 1, wc = wave & 1;
  const int bid = blockIdx.x;
  const int swz = ((bid & 7) << 8) | (bid >> 3);
  const int bcol = (swz & 7) * 128;
  const int brow = (swz >> 3) * 128;

  const f32x4 zero = {0.f,0.f,0.f,0.f};
  f32x4 acc[4][4];
  #pragma unroll
  for (int a=0;a<4;a++)
    #pragma unroll
    for (int b=0;b<4;b++) acc[a][b]=zero;

  const int kt_res = (bcol >> 6) + wc;   // wave-uniform

  for (int kt = 0; kt < D_MODEL/64; ++kt){
    __syncthreads();
    #pragma unroll
    for (int i=0;i<4;i++){
      const int ob = i*256 + wave*64;
      const int o  = ob + lane;
      const int r  = o >> 3;
      const int c  = ((o & 7) ^ (r & 7)) * 16;
      gload16((const char*)Sb  + (size_t)(brow + r)*(D_MODEL*2) + (size_t)kt*128 + c,
              (char*)sA + (size_t)ob*16);
      gload16((const char*)Wob + (size_t)(bcol + r)*(D_MODEL*2) + (size_t)kt*128 + c,
              (char*)sB + (size_t)ob*16);
    }
    __syncthreads();
    #pragma unroll
    for (int ks=0; ks<2; ++ks){
      s16x8 af[4], bf[4];
      #pragma unroll
      for (int mi=0; mi<4; mi++){
        const int row = wr*64 + mi*16 + (lane & 15);
        const int chunk = (ks*4 + (lane>>4)) ^ (row & 7);
        af[mi] = *(const s16x8*)((const char*)sA + row*128 + chunk*16);
      }
      #pragma unroll
      for (int ni=0; ni<4; ni++){
        const int n = wc*64 + ni*16 + (lane & 15);
        const int chunk = (ks*4 + (lane>>4)) ^ (n & 7);
        bf[ni] = *(const s16x8*)((const char*)sB + n*128 + chunk*16);
      }
      #pragma unroll
      for (int mi=0; mi<4; mi++)
        #pragma unroll
        for (int ni=0; ni<4; ni++)
          acc[mi][ni] = __builtin_amdgcn_mfma_f32_16x16x32_bf16(af[mi], bf[ni], acc[mi][ni], 0,0,0);
    }
    if (kt == kt_res){
      // residual snag: states[row][col] from sA (valid until next barrier)
      #pragma unroll
      for (int ni=0; ni<4; ni++){
        #pragma unroll
        for (int mi=0; mi<4; mi++){
          #pragma unroll
          for (int q=0; q<4; q++){
            const int rl = wr*64 + mi*16 + ((lane>>4)*4) + q;
            const int cl = ni*16 + (lane & 15);
            const int byte = rl*128 + (((cl>>3) ^ (rl&7))*16) + ((cl&7)*2);
            acc[mi][ni][q] += bf2f((unsigned int)*(const unsigned short*)((const char*)sA + byte));
          }
        }
      }
    }
  }

  #pragma unroll
  for (int ni=0; ni<4; ni++){
    const int col = bcol + wc*64 + ni*16 + (lane & 15);
    const float vb = b_out[col];
    #pragma unroll
    for (int mi=0; mi<4; mi++){
      #pragma unroll
      for (int q=0; q<4; q++){
        const int row = brow + wr*64 + mi*16 + ((lane>>4)*4) + q;
        yb[(size_t)row*D_MODEL + col] = f2bf(acc[mi][ni][q] + vb);
      }
    }
  }
}

// ---------------- LayerNorm (y already includes residual, bf16) ----------------
__global__ __launch_bounds__(256)
void ln_kernel(const unsigned short* __restrict__ yb,
               const float* __restrict__ gamma, const float* __restrict__ beta,
               float* __restrict__ out)
{
  const int row = blockIdx.x;
  const int tid = threadIdx.x;
  ushort4 yv = ((const ushort4*)(yb + (size_t)row*D_MODEL))[tid];
  float4 v;
  v.x = bf2f(yv.x); v.y = bf2f(yv.y); v.z = bf2f(yv.z); v.w = bf2f(yv.w);
  float s = v.x+v.y+v.z+v.w;
  float q = v.x*v.x + v.y*v.y + v.z*v.z + v.w*v.w;
  #pragma unroll
  for (int off=32; off>0; off>>=1){ s += __shfl_xor(s, off); q += __shfl_xor(q, off); }
  __shared__ float rs[4], rq[4];
  const int wave = tid>>6, lane = tid&63;
  if (lane==0){ rs[wave]=s; rq[wave]=q; }
  __syncthreads();
  float ts = rs[0]+rs[1]+rs[2]+rs[3];
  float tq = rq[0]+rq[1]+rq[2]+rq[3];
  float mu  = ts * (1.f/D_MODEL);
  float var = tq * (1.f/D_MODEL) - mu*mu;
  float inv = rsqrtf(var + 1e-5f);
  float4 g = ((const float4*)gamma)[tid];
  float4 b = ((const float4*)beta)[tid];
  float4 o;
  o.x = (v.x-mu)*inv*g.x + b.x;
  o.y = (v.y-mu)*inv*g.y + b.y;
  o.z = (v.z-mu)*inv*g.z + b.z;
  o.w = (v.w-mu)*inv*g.w + b.w;
  ((float4*)(out + (size_t)row*D_MODEL))[tid] = o;
}

extern "C" void kernel_launch(void* const* d_in, const int* in_sizes, int n_in,
                              void* d_out, int out_size, void* d_ws, size_t ws_size,
                              hipStream_t stream) {
  const float* x         = (const float*)d_in[0];
  const float* delta     = (const float*)d_in[1];
  const float* log_decay = (const float*)d_in[2];
  const float* W_in      = (const float*)d_in[3];
  const float* b_in      = (const float*)d_in[4];
  const float* W_gate    = (const float*)d_in[5];
  const float* b_gate    = (const float*)d_in[6];
  const float* W_out     = (const float*)d_in[7];
  const float* b_out     = (const float*)d_in[8];
  const float* gamma     = (const float*)d_in[9];
  const float* beta      = (const float*)d_in[10];

  char* w = (char*)d_ws;
  unsigned short* xb   = (unsigned short*)(w);                 // 64 MiB, reused as statesb
  unsigned short* Wugb = (unsigned short*)(w + 67108864);      // 4 MiB (interleaved Wi/Wg groups)
  unsigned short* Wob  = (unsigned short*)(w + 71303168);      // 2 MiB
  float*          decay= (float*)        (w + 73400320);       // 4 KiB
  float*          cA   = (float*)        (w + 73404416);       // 2 MiB
  float*          cB   = (float*)        (w + 75501568);       // 2 MiB
  float*          cS   = (float*)        (w + 77598720);       // 2 MiB
  unsigned int*   pack = (unsigned int*) (w + 79695872);       // 128 MiB; first half reused as y(bf16)
  unsigned short* ybuf = (unsigned short*)pack;
  unsigned short* statesb = xb;

  float* out    = (float*)d_out;
  float* fstate = out + (size_t)MROWS*D_MODEL;

  hipLaunchKernelGGL(prep_all_kernel, dim3(9216), dim3(256), 0, stream,
                     x, W_in, W_gate, W_out, log_decay, xb, Wugb, Wob, decay, MROWS*D_MODEL/4);
  // slim dual GEMM: pack = {drive, 1-lambda} + fused chunk summaries (passA gone)
  hipLaunchKernelGGL(gemm_dual64_kernel, dim3(4096), dim3(256), 0, stream,
                     xb, Wugb, b_in, b_gate, decay, delta, pack, cA, cB);
  hipLaunchKernelGGL(scan_passB, dim3(2,BATCH), dim3(256), 0, stream, cA, cB, cS, fstate);
  hipLaunchKernelGGL(scan_passC, dim3(2,NC,BATCH), dim3(256), 0, stream, pack, cS, statesb);
  // out-pass with fused residual: ybuf = bf16(states Wout^T + b_out + states)
  hipLaunchKernelGGL(gemm_out_kernel, dim3(2048), dim3(256), 0, stream,
                     statesb, Wob, b_out, ybuf);
  hipLaunchKernelGGL(ln_kernel, dim3(MROWS), dim3(256), 0, stream, ybuf, gamma, beta, out);
}